// Round 4
// baseline (84.832 us; speedup 1.0000x reference)
//
#include <hip/hip_runtime.h>
#include <math.h>

#define BS 64
#define MUX_IN 8192
#define MUX_OUT 128
#define EPSF 1e-20f

#define NBLK 512
#define ROWS_PER_BLK 16              // 512 * 16 = 8192 output rows
#define ROW4 (MUX_IN / 4)            // float4s per row

typedef unsigned int u32;
typedef unsigned long long u64;

// Map fp32 to monotonically-increasing unsigned key
__device__ __forceinline__ u32 sortable_f32(float f) {
    u32 b = __float_as_uint(f);
    return (b & 0x80000000u) ? ~b : (b | 0x80000000u);
}

// ---------------------------------------------------------------------------
// Single cooperative kernel, 512 blocks x 256 threads (2 blocks/CU,
// co-residency guaranteed by cooperative launch => spin-wait is deadlock-free).
//
//   blocks 0..63 : radix-select top-128 for batch row b (keys in registers),
//                  write topk, device-scope release + done++ ... then fall
//                  through to the fill phase like everyone else.
//   all blocks   : zero-fill their own 16 contiguous output rows (268 MB
//                  total, BW-saturated from t=0 by the 448 non-select blocks,
//                  so select is fully hidden), then acquire-spin on done==64
//                  (already satisfied by fill completion) and write the 16
//                  1.0f's into rows this block itself zeroed (same-block
//                  ordering: __syncthreads drains vmcnt before the barrier).
// ---------------------------------------------------------------------------
__global__ __launch_bounds__(256) void fused_all(
        const float* __restrict__ logits,
        const float* __restrict__ u,
        int* __restrict__ topk,
        u32* __restrict__ done,
        float* __restrict__ out) {
    const int t = threadIdx.x;
    const int blk = blockIdx.x;

    __shared__ u32 hist[4][256];
    __shared__ u32 suf[256];
    __shared__ int sK;
    __shared__ u32 sSel;
    __shared__ int cnt;
    __shared__ u64 list[256];

    if (blk < BS) {
        // ---------------- select phase (one block per batch row) ----------
        const int b = blk;
        const float* __restrict__ urow = u + (size_t)b * MUX_IN;

        u32 kv[32];
#pragma unroll
        for (int q = 0; q < 8; ++q) {
            const int base = q * 1024 + t * 4;
            const float4 uu = *(const float4*)(urow + base);
            const float4 lg = *(const float4*)(logits + base);
            float in0 = -logf(uu.x + EPSF) + EPSF; kv[q * 4 + 0] = sortable_f32(lg.x - logf(in0));
            float in1 = -logf(uu.y + EPSF) + EPSF; kv[q * 4 + 1] = sortable_f32(lg.y - logf(in1));
            float in2 = -logf(uu.z + EPSF) + EPSF; kv[q * 4 + 2] = sortable_f32(lg.z - logf(in2));
            float in3 = -logf(uu.w + EPSF) + EPSF; kv[q * 4 + 3] = sortable_f32(lg.w - logf(in3));
        }
        // element index of kv[k]: (k>>2)*1024 + t*4 + (k&3)

        if (t == 0) { sK = MUX_OUT; sSel = 0u; cnt = 0; }
        const int wv = t >> 6;

        for (int pass = 0; pass < 4; ++pass) {
            const int sh = 24 - pass * 8;
#pragma unroll
            for (int w = 0; w < 4; ++w) hist[w][t] = 0u;
            __syncthreads();

            const u32 mask = (pass == 0) ? 0u : (0xFFFFFFFFu << (sh + 8));
            const u32 sel = sSel;
            const int K = sK;
#pragma unroll
            for (int k = 0; k < 32; ++k) {
                if (((kv[k] ^ sel) & mask) == 0u)
                    atomicAdd(&hist[wv][(kv[k] >> sh) & 255u], 1u);
            }
            __syncthreads();

            const u32 c = hist[0][t] + hist[1][t] + hist[2][t] + hist[3][t];
            suf[t] = c;
            __syncthreads();
            for (int off = 1; off < 256; off <<= 1) {
                const u32 v = suf[t] + ((t + off < 256) ? suf[t + off] : 0u);
                __syncthreads();
                suf[t] = v;
                __syncthreads();
            }
            const u32 gt = (t < 255) ? suf[t + 1] : 0u;
            if ((int)gt < K && (int)(gt + c) >= K) {   // exactly one thread
                sSel = sel | ((u32)t << sh);
                sK = K - (int)gt;
            }
            __syncthreads();
        }

        const u32 T = sSel;                 // 128th-largest key value
#pragma unroll
        for (int k = 0; k < 32; ++k) {
            if (kv[k] >= T) {
                const int slot = atomicAdd(&cnt, 1);
                if (slot < 256) {
                    const int gi = (k >> 2) * 1024 + t * 4 + (k & 3);
                    list[slot] = ((u64)kv[k] << 32) | (u32)(MUX_IN - 1 - gi);
                }
            }
        }
        __syncthreads();
        int c0 = cnt; if (c0 > 256) c0 = 256;
        for (int idx = c0 + t; idx < 256; idx += 256) list[idx] = 0ull;
        __syncthreads();

        // bitonic sort 256 u64, descending; ties -> lower element index first
        for (int kk = 2; kk <= 256; kk <<= 1) {
            for (int j = kk >> 1; j > 0; j >>= 1) {
                const int ixj = t ^ j;
                if (ixj > t) {
                    const u64 a = list[t];
                    const u64 bb = list[ixj];
                    const bool desc = ((t & kk) == 0);
                    if (desc ? (a < bb) : (a > bb)) { list[t] = bb; list[ixj] = a; }
                }
                __syncthreads();
            }
        }

        if (t < MUX_OUT) {
            const u64 e = list[t];
            topk[b * MUX_OUT + t] = MUX_IN - 1 - (int)(e & 0xFFFFFFFFull);
        }
        __syncthreads();
        if (t == 0) {
            __threadfence();   // publish topk device-wide before signalling
            __hip_atomic_fetch_add(done, 1u, __ATOMIC_RELEASE,
                                   __HIP_MEMORY_SCOPE_AGENT);
        }
    }

    // ---------------- fill phase: this block's 16 contiguous rows ----------
    {
        float4* __restrict__ o4 =
            (float4*)(out + (size_t)blk * ROWS_PER_BLK * MUX_IN);
        const float4 z = make_float4(0.f, 0.f, 0.f, 0.f);
        const int n4 = ROWS_PER_BLK * ROW4;          // 32768 float4s
        for (int p = t; p < n4; p += 256) o4[p] = z;
    }

    __syncthreads();   // drains vmcnt: all zero-stores of this block complete
    if (t == 0) {
        while (__hip_atomic_load(done, __ATOMIC_ACQUIRE,
                                 __HIP_MEMORY_SCOPE_AGENT) < BS) {
            __builtin_amdgcn_s_sleep(2);
        }
    }
    __syncthreads();

    // ---------------- ones phase: rows this block itself zeroed ------------
    if (t < ROWS_PER_BLK) {
        const int row = blk * ROWS_PER_BLK + t;      // 0..8191
        const int idx = __hip_atomic_load(&topk[row], __ATOMIC_ACQUIRE,
                                          __HIP_MEMORY_SCOPE_AGENT);
        out[(size_t)row * MUX_IN + idx] = 1.0f;
    }
}

extern "C" void kernel_launch(void* const* d_in, const int* in_sizes, int n_in,
                              void* d_out, int out_size, void* d_ws, size_t ws_size,
                              hipStream_t stream) {
    const float* logits = (const float*)d_in[0];   // (1, 8192)
    // d_in[1] = inpData: not needed for the output
    const float* u = (const float*)d_in[2];        // (64, 1, 8192)
    float* out = (float*)d_out;                    // (64, 128, 8192) fp32

    int* topk = (int*)d_ws;                        // 64*128 ints = 32 KB
    u32* done = (u32*)((char*)d_ws + BS * MUX_OUT * sizeof(int));

    // reset the arrival counter every call (graph replays don't re-poison ws)
    hipMemsetAsync(done, 0, sizeof(u32), stream);

    void* args[] = {(void*)&logits, (void*)&u, (void*)&topk,
                    (void*)&done, (void*)&out};
    hipLaunchCooperativeKernel((const void*)fused_all, dim3(NBLK), dim3(256),
                               args, 0, stream);
}

// Round 6
// 52.814 us; speedup vs baseline: 1.6062x; 1.6062x over previous
//
#include <hip/hip_runtime.h>
#include <math.h>

#define BS 64
#define MUX_IN 8192
#define MUX_OUT 128
#define EPSF 1e-20f

#define NFILL_BLOCKS 1984
#define NBLOCKS (64 + NFILL_BLOCKS)
#define OUT_FLOAT4 ((size_t)BS * MUX_OUT * MUX_IN / 4)   // 16,777,216

typedef unsigned int u32;
typedef unsigned long long u64;
typedef float f32x4 __attribute__((ext_vector_type(4)));   // native vec for nt-store

// Map fp32 to monotonically-increasing unsigned key
__device__ __forceinline__ u32 sortable_f32(float f) {
    u32 b = __float_as_uint(f);
    return (b & 0x80000000u) ? ~b : (b | 0x80000000u);
}

// ---------------------------------------------------------------------------
// Fused kernel (round-3 proven structure):
//   blocks 0..63      : per-row keys (in-register) + radix-select + bitonic
//                       sort -> topk[b*128..] (exact jax.lax.top_k order)
//   blocks 64..2047   : grid-stride zero-fill of the whole 268 MB output,
//                       nontemporal 16B stores (streaming, zero reuse)
// No inter-block dependencies -> normal launch; select hides under fill.
// ---------------------------------------------------------------------------
__global__ __launch_bounds__(256) void fused_kernel(
        const float* __restrict__ logits,
        const float* __restrict__ u,
        int* __restrict__ topk,
        float* __restrict__ out) {
    const int t = threadIdx.x;

    if (blockIdx.x >= 64) {
        // ---------------- zero-fill path ----------------
        const size_t tid = (size_t)(blockIdx.x - 64) * 256 + t;
        const size_t nthreads = (size_t)NFILL_BLOCKS * 256;
        f32x4* __restrict__ o4 = (f32x4*)out;
        const f32x4 z = {0.f, 0.f, 0.f, 0.f};
        for (size_t p = tid; p < OUT_FLOAT4; p += nthreads)
            __builtin_nontemporal_store(z, o4 + p);
        return;
    }

    // ---------------- select path (one block per batch row) ----------------
    const int b = blockIdx.x;
    const float* __restrict__ urow = u + (size_t)b * MUX_IN;

    // compute this row's 8192 sortable keys, 32 per thread, in registers
    u32 kv[32];
#pragma unroll
    for (int q = 0; q < 8; ++q) {
        const int base = q * 1024 + t * 4;
        const float4 uu = *(const float4*)(urow + base);
        const float4 lg = *(const float4*)(logits + base);
        float in0 = -logf(uu.x + EPSF) + EPSF; kv[q * 4 + 0] = sortable_f32(lg.x - logf(in0));
        float in1 = -logf(uu.y + EPSF) + EPSF; kv[q * 4 + 1] = sortable_f32(lg.y - logf(in1));
        float in2 = -logf(uu.z + EPSF) + EPSF; kv[q * 4 + 2] = sortable_f32(lg.z - logf(in2));
        float in3 = -logf(uu.w + EPSF) + EPSF; kv[q * 4 + 3] = sortable_f32(lg.w - logf(in3));
    }
    // element index of kv[k] within the row: (k>>2)*1024 + t*4 + (k&3)

    __shared__ u32 hist[4][256];      // wave-private copies
    __shared__ u32 suf[256];
    __shared__ int sK;
    __shared__ u32 sSel;
    __shared__ int cnt;
    __shared__ u64 list[256];

    if (t == 0) { sK = MUX_OUT; sSel = 0u; cnt = 0; }
    const int wv = t >> 6;

    // 4x 8-bit radix passes narrowing to the 128th-largest key value
    for (int pass = 0; pass < 4; ++pass) {
        const int sh = 24 - pass * 8;
#pragma unroll
        for (int w = 0; w < 4; ++w) hist[w][t] = 0u;
        __syncthreads();

        const u32 mask = (pass == 0) ? 0u : (0xFFFFFFFFu << (sh + 8));
        const u32 sel = sSel;
        const int K = sK;
#pragma unroll
        for (int k = 0; k < 32; ++k) {
            if (((kv[k] ^ sel) & mask) == 0u)
                atomicAdd(&hist[wv][(kv[k] >> sh) & 255u], 1u);
        }
        __syncthreads();

        const u32 c = hist[0][t] + hist[1][t] + hist[2][t] + hist[3][t];
        suf[t] = c;
        __syncthreads();
        // inclusive suffix sum over suf[0..255]
        for (int off = 1; off < 256; off <<= 1) {
            const u32 v = suf[t] + ((t + off < 256) ? suf[t + off] : 0u);
            __syncthreads();
            suf[t] = v;
            __syncthreads();
        }
        const u32 gt = (t < 255) ? suf[t + 1] : 0u;   // keys in bins > t
        if ((int)gt < K && (int)(gt + c) >= K) {       // exactly one thread
            sSel = sel | ((u32)t << sh);
            sK = K - (int)gt;
        }
        __syncthreads();
    }

    // T = 128th-largest key. Collect all keys >= T.
    const u32 T = sSel;
#pragma unroll
    for (int k = 0; k < 32; ++k) {
        if (kv[k] >= T) {
            const int slot = atomicAdd(&cnt, 1);
            if (slot < 256) {
                const int gi = (k >> 2) * 1024 + t * 4 + (k & 3);
                list[slot] = ((u64)kv[k] << 32) | (u32)(MUX_IN - 1 - gi);
            }
        }
    }
    __syncthreads();
    int c0 = cnt; if (c0 > 256) c0 = 256;
    for (int idx = c0 + t; idx < 256; idx += 256) list[idx] = 0ull;
    __syncthreads();

    // Bitonic sort 256 u64 entries, descending; ties -> lower element index
    // first (matches jax.lax.top_k).
    for (int kk = 2; kk <= 256; kk <<= 1) {
        for (int j = kk >> 1; j > 0; j >>= 1) {
            const int ixj = t ^ j;
            if (ixj > t) {
                const u64 a = list[t];
                const u64 bb = list[ixj];
                const bool desc = ((t & kk) == 0);
                if (desc ? (a < bb) : (a > bb)) { list[t] = bb; list[ixj] = a; }
            }
            __syncthreads();
        }
    }

    if (t < MUX_OUT) {
        const u64 e = list[t];
        topk[b * MUX_OUT + t] = MUX_IN - 1 - (int)(e & 0xFFFFFFFFull);
    }
}

// ---------------------------------------------------------------------------
// Ones kernel: 8192 scattered 1.0f stores. Separate launch => kernel-boundary
// coherence orders these after the zero-fill (no cross-XCD WAW hazard).
// ---------------------------------------------------------------------------
__global__ __launch_bounds__(256) void ones_kernel(
        const int* __restrict__ topk,
        float* __restrict__ out) {
    const int r = blockIdx.x * 256 + threadIdx.x;   // output row 0..8191
    out[(size_t)r * MUX_IN + topk[r]] = 1.0f;
}

extern "C" void kernel_launch(void* const* d_in, const int* in_sizes, int n_in,
                              void* d_out, int out_size, void* d_ws, size_t ws_size,
                              hipStream_t stream) {
    const float* logits = (const float*)d_in[0];   // (1, 8192)
    // d_in[1] = inpData: not needed for the output
    const float* u = (const float*)d_in[2];        // (64, 1, 8192)
    float* out = (float*)d_out;                    // (64, 128, 8192) fp32
    int* topk = (int*)d_ws;                        // 64*128 ints = 32 KB

    fused_kernel<<<NBLOCKS, 256, 0, stream>>>(logits, u, topk, out);
    ones_kernel<<<(BS * MUX_OUT) / 256, 256, 0, stream>>>(topk, out);
}

// Round 7
// 42.428 us; speedup vs baseline: 1.9994x; 1.2448x over previous
//
#include <hip/hip_runtime.h>
#include <math.h>

#define BS 64
#define MUX_IN 8192
#define MUX_OUT 128
#define EPSF 1e-20f

#define NFILL_BLOCKS 1984
#define NBLOCKS (64 + NFILL_BLOCKS)
#define OUT_FLOAT4 ((size_t)BS * MUX_OUT * MUX_IN / 4)   // 16,777,216

typedef unsigned int u32;
typedef unsigned long long u64;

// Map fp32 to monotonically-increasing unsigned key
__device__ __forceinline__ u32 sortable_f32(float f) {
    u32 b = __float_as_uint(f);
    return (b & 0x80000000u) ? ~b : (b | 0x80000000u);
}

// ---------------------------------------------------------------------------
// Fused kernel (round-3 proven structure, reverted from nt-store regression):
//   blocks 0..63      : per-row keys (in-register) + radix-select + bitonic
//                       sort -> topk[b*128..] (exact jax.lax.top_k order)
//   blocks 64..2047   : grid-stride zero-fill of the whole 268 MB output
//                       with plain float4 stores (fastest fill path on gfx950;
//                       nontemporal stores measured 24% SLOWER)
// No inter-block dependencies -> normal launch; select hides under fill.
// ---------------------------------------------------------------------------
__global__ __launch_bounds__(256) void fused_kernel(
        const float* __restrict__ logits,
        const float* __restrict__ u,
        int* __restrict__ topk,
        float* __restrict__ out) {
    const int t = threadIdx.x;

    if (blockIdx.x >= 64) {
        // ---------------- zero-fill path ----------------
        const size_t tid = (size_t)(blockIdx.x - 64) * 256 + t;
        const size_t nthreads = (size_t)NFILL_BLOCKS * 256;
        float4* __restrict__ o4 = (float4*)out;
        const float4 z = make_float4(0.f, 0.f, 0.f, 0.f);
        for (size_t p = tid; p < OUT_FLOAT4; p += nthreads) o4[p] = z;
        return;
    }

    // ---------------- select path (one block per batch row) ----------------
    const int b = blockIdx.x;
    const float* __restrict__ urow = u + (size_t)b * MUX_IN;

    // compute this row's 8192 sortable keys, 32 per thread, in registers
    u32 kv[32];
#pragma unroll
    for (int q = 0; q < 8; ++q) {
        const int base = q * 1024 + t * 4;
        const float4 uu = *(const float4*)(urow + base);
        const float4 lg = *(const float4*)(logits + base);
        float in0 = -logf(uu.x + EPSF) + EPSF; kv[q * 4 + 0] = sortable_f32(lg.x - logf(in0));
        float in1 = -logf(uu.y + EPSF) + EPSF; kv[q * 4 + 1] = sortable_f32(lg.y - logf(in1));
        float in2 = -logf(uu.z + EPSF) + EPSF; kv[q * 4 + 2] = sortable_f32(lg.z - logf(in2));
        float in3 = -logf(uu.w + EPSF) + EPSF; kv[q * 4 + 3] = sortable_f32(lg.w - logf(in3));
    }
    // element index of kv[k] within the row: (k>>2)*1024 + t*4 + (k&3)

    __shared__ u32 hist[4][256];      // wave-private copies
    __shared__ u32 suf[256];
    __shared__ int sK;
    __shared__ u32 sSel;
    __shared__ int cnt;
    __shared__ u64 list[256];

    if (t == 0) { sK = MUX_OUT; sSel = 0u; cnt = 0; }
    const int wv = t >> 6;

    // 4x 8-bit radix passes narrowing to the 128th-largest key value
    for (int pass = 0; pass < 4; ++pass) {
        const int sh = 24 - pass * 8;
#pragma unroll
        for (int w = 0; w < 4; ++w) hist[w][t] = 0u;
        __syncthreads();

        const u32 mask = (pass == 0) ? 0u : (0xFFFFFFFFu << (sh + 8));
        const u32 sel = sSel;
        const int K = sK;
#pragma unroll
        for (int k = 0; k < 32; ++k) {
            if (((kv[k] ^ sel) & mask) == 0u)
                atomicAdd(&hist[wv][(kv[k] >> sh) & 255u], 1u);
        }
        __syncthreads();

        const u32 c = hist[0][t] + hist[1][t] + hist[2][t] + hist[3][t];
        suf[t] = c;
        __syncthreads();
        // inclusive suffix sum over suf[0..255]
        for (int off = 1; off < 256; off <<= 1) {
            const u32 v = suf[t] + ((t + off < 256) ? suf[t + off] : 0u);
            __syncthreads();
            suf[t] = v;
            __syncthreads();
        }
        const u32 gt = (t < 255) ? suf[t + 1] : 0u;   // keys in bins > t
        if ((int)gt < K && (int)(gt + c) >= K) {       // exactly one thread
            sSel = sel | ((u32)t << sh);
            sK = K - (int)gt;
        }
        __syncthreads();
    }

    // T = 128th-largest key. Collect all keys >= T.
    const u32 T = sSel;
#pragma unroll
    for (int k = 0; k < 32; ++k) {
        if (kv[k] >= T) {
            const int slot = atomicAdd(&cnt, 1);
            if (slot < 256) {
                const int gi = (k >> 2) * 1024 + t * 4 + (k & 3);
                list[slot] = ((u64)kv[k] << 32) | (u32)(MUX_IN - 1 - gi);
            }
        }
    }
    __syncthreads();
    int c0 = cnt; if (c0 > 256) c0 = 256;
    for (int idx = c0 + t; idx < 256; idx += 256) list[idx] = 0ull;
    __syncthreads();

    // Bitonic sort 256 u64 entries, descending; ties -> lower element index
    // first (matches jax.lax.top_k).
    for (int kk = 2; kk <= 256; kk <<= 1) {
        for (int j = kk >> 1; j > 0; j >>= 1) {
            const int ixj = t ^ j;
            if (ixj > t) {
                const u64 a = list[t];
                const u64 bb = list[ixj];
                const bool desc = ((t & kk) == 0);
                if (desc ? (a < bb) : (a > bb)) { list[t] = bb; list[ixj] = a; }
            }
            __syncthreads();
        }
    }

    if (t < MUX_OUT) {
        const u64 e = list[t];
        topk[b * MUX_OUT + t] = MUX_IN - 1 - (int)(e & 0xFFFFFFFFull);
    }
}

// ---------------------------------------------------------------------------
// Ones kernel: 8192 scattered 1.0f stores. Separate launch => kernel-boundary
// coherence orders these after the zero-fill (no cross-XCD WAW hazard).
// ---------------------------------------------------------------------------
__global__ __launch_bounds__(256) void ones_kernel(
        const int* __restrict__ topk,
        float* __restrict__ out) {
    const int r = blockIdx.x * 256 + threadIdx.x;   // output row 0..8191
    out[(size_t)r * MUX_IN + topk[r]] = 1.0f;
}

extern "C" void kernel_launch(void* const* d_in, const int* in_sizes, int n_in,
                              void* d_out, int out_size, void* d_ws, size_t ws_size,
                              hipStream_t stream) {
    const float* logits = (const float*)d_in[0];   // (1, 8192)
    // d_in[1] = inpData: not needed for the output
    const float* u = (const float*)d_in[2];        // (64, 1, 8192)
    float* out = (float*)d_out;                    // (64, 128, 8192) fp32
    int* topk = (int*)d_ws;                        // 64*128 ints = 32 KB

    fused_kernel<<<NBLOCKS, 256, 0, stream>>>(logits, u, topk, out);
    ones_kernel<<<(BS * MUX_OUT) / 256, 256, 0, stream>>>(topk, out);
}